// Round 13
// baseline (112.415 us; speedup 1.0000x reference)
//
#include <hip/hip_runtime.h>
#include <math.h>

#define B_SZ 8
#define T_SZ 2048
#define C_SZ 1024
#define EPSF 1e-6f
#define QSCALE (6.5f / 127.0f)
#define QINV   (127.0f / 6.5f)

typedef float        f32x4 __attribute__((ext_vector_type(4)));
typedef unsigned int u32;
typedef u32          u32x2 __attribute__((ext_vector_type(2)));

// ---------------------------------------------------------------------------
// logits_part (256 floats) -> sinkhorn -> wgt[B][4]. Call with 256 threads.
// ---------------------------------------------------------------------------
__device__ __forceinline__ void compute_weights(const float* __restrict__ logits_part,
                                                float lp[256], float lg[32],
                                                float wgt[B_SZ][4], int tid) {
    lp[tid] = logits_part[tid];
    __syncthreads();
    if (tid < 32) {
        float s = 0.f;
#pragma unroll
        for (int g = 0; g < 8; ++g) s += lp[tid * 8 + g];
        lg[tid] = s;               // logits[b*4+k]
    }
    __syncthreads();
    if (tid < B_SZ) {
        int b = tid;
        float L[4];
#pragma unroll
        for (int i = 0; i < 4; ++i) L[i] = lg[b * 4 + i];
        float mx = fmaxf(fmaxf(L[0], L[1]), fmaxf(L[2], L[3]));
        float m = 2.0f * mx;
        float t[4][4];
#pragma unroll
        for (int i = 0; i < 4; ++i)
#pragma unroll
            for (int j = 0; j < 4; ++j)
                t[i][j] = fmaxf(expf(L[i] + L[j] - m), EPSF);
#pragma unroll
        for (int it = 0; it < 5; ++it) {
#pragma unroll
            for (int i = 0; i < 4; ++i) {
                float rs = t[i][0] + t[i][1] + t[i][2] + t[i][3] + EPSF;
#pragma unroll
                for (int j = 0; j < 4; ++j) t[i][j] /= rs;
            }
#pragma unroll
            for (int j = 0; j < 4; ++j) {
                float cs = t[0][j] + t[1][j] + t[2][j] + t[3][j] + EPSF;
#pragma unroll
                for (int i = 0; i < 4; ++i) t[i][j] /= cs;
            }
        }
#pragma unroll
        for (int i = 0; i < 4; ++i) {
            float rs = t[i][0] + t[i][1] + t[i][2] + t[i][3] + EPSF;
#pragma unroll
            for (int j = 0; j < 4; ++j) t[i][j] /= rs;
        }
        float w[4];
#pragma unroll
        for (int j = 0; j < 4; ++j)
            w[j] = 0.25f * (t[0][j] + t[1][j] + t[2][j] + t[3][j]);
        float s = w[0] + w[1] + w[2] + w[3] + EPSF;
#pragma unroll
        for (int j = 0; j < 4; ++j) w[j] /= s;
        bool fin = isfinite(w[0]) && isfinite(w[1]) && isfinite(w[2]) && isfinite(w[3]);
#pragma unroll
        for (int j = 0; j < 4; ++j)
            wgt[b][j] = fin ? w[j] : 0.25f;
    }
    __syncthreads();
}

__device__ __forceinline__ u32 quant4(f32x4 v) {
    f32x4 q = v * QINV;
    int q0 = (int)rintf(fminf(fmaxf(q.x, -127.f), 127.f));
    int q1 = (int)rintf(fminf(fmaxf(q.y, -127.f), 127.f));
    int q2 = (int)rintf(fminf(fmaxf(q.z, -127.f), 127.f));
    int q3 = (int)rintf(fminf(fmaxf(q.w, -127.f), 127.f));
    return (u32)(q0 & 255) | ((u32)(q1 & 255) << 8) |
           ((u32)(q2 & 255) << 16) | ((u32)(q3 & 255) << 24);
}

__device__ __forceinline__ f32x4 dec4(u32 x) {
    f32x4 r;
    r.x = (float)(signed char)(x & 0xFF);
    r.y = (float)(signed char)((x >> 8) & 0xFF);
    r.z = (float)(signed char)((x >> 16) & 0xFF);
    r.w = (float)(signed char)((x >> 24) & 0xFF);
    return r;
}

// ---------------------------------------------------------------------------
// Kernel 1: partial mean over T + int8 quantized copy.
// 512 blocks, 256 threads, 128 rows/block. A/B vs R12: loads are REGULAR
// cached (single-variable test of "NT loads are intrinsically slower" vs
// "NT protects qs L3 residency"). Everything else identical to R12.
// ---------------------------------------------------------------------------
__global__ void pool_quant(const float* __restrict__ br,
                           float* __restrict__ part,
                           u32* __restrict__ qs) {
    const int chunk = blockIdx.x & 31;   // b*4 + k
    const int seg   = blockIdx.x >> 5;   // 0..15
    const int b = chunk >> 2;
    const int k = chunk & 3;
    const int t0 = seg * 128;

    const f32x4* src = (const f32x4*)(br + (size_t)(k * B_SZ + b) * T_SZ * C_SZ);
    u32* qdst = qs + (size_t)(k * B_SZ + b) * T_SZ * (C_SZ / 4);
    const int c4 = threadIdx.x;          // 0..255 covers C/4

    f32x4 acc0 = (f32x4)(0.f), acc1 = (f32x4)(0.f);
    f32x4 acc2 = (f32x4)(0.f), acc3 = (f32x4)(0.f);
    for (int t = t0; t < t0 + 128; t += 8) {
        const size_t r0 = (size_t)t * (C_SZ / 4) + c4;
        f32x4 v0 = src[r0 + 0 * (C_SZ / 4)];
        f32x4 v1 = src[r0 + 1 * (C_SZ / 4)];
        f32x4 v2 = src[r0 + 2 * (C_SZ / 4)];
        f32x4 v3 = src[r0 + 3 * (C_SZ / 4)];
        f32x4 v4 = src[r0 + 4 * (C_SZ / 4)];
        f32x4 v5 = src[r0 + 5 * (C_SZ / 4)];
        f32x4 v6 = src[r0 + 6 * (C_SZ / 4)];
        f32x4 v7 = src[r0 + 7 * (C_SZ / 4)];
        acc0 += v0; acc1 += v1; acc2 += v2; acc3 += v3;
        acc0 += v4; acc1 += v5; acc2 += v6; acc3 += v7;
        qdst[r0 + 0 * (C_SZ / 4)] = quant4(v0);
        qdst[r0 + 1 * (C_SZ / 4)] = quant4(v1);
        qdst[r0 + 2 * (C_SZ / 4)] = quant4(v2);
        qdst[r0 + 3 * (C_SZ / 4)] = quant4(v3);
        qdst[r0 + 4 * (C_SZ / 4)] = quant4(v4);
        qdst[r0 + 5 * (C_SZ / 4)] = quant4(v5);
        qdst[r0 + 6 * (C_SZ / 4)] = quant4(v6);
        qdst[r0 + 7 * (C_SZ / 4)] = quant4(v7);
    }
    f32x4 acc = (acc0 + acc1) + (acc2 + acc3);
    ((f32x4*)(part + ((size_t)seg * 32 + chunk) * C_SZ))[c4] = acc;
}

// ---------------------------------------------------------------------------
// Kernel 1 (fallback, fp32): partial mean only.
// ---------------------------------------------------------------------------
__global__ void pool_partial(const float* __restrict__ br,
                             float* __restrict__ part) {
    const int chunk = blockIdx.x & 31;
    const int seg   = blockIdx.x >> 5;
    const int b = chunk >> 2;
    const int k = chunk & 3;
    const int t0 = seg * 128;

    const f32x4* src = (const f32x4*)(br + (size_t)(k * B_SZ + b) * T_SZ * C_SZ);
    const int c4 = threadIdx.x;
    f32x4 acc = (f32x4)(0.f);
#pragma unroll 4
    for (int t = t0; t < t0 + 128; ++t) {
        acc += src[(size_t)t * (C_SZ / 4) + c4];
    }
    ((f32x4*)(part + ((size_t)seg * 32 + chunk) * C_SZ))[c4] = acc;
}

// ---------------------------------------------------------------------------
// Kernel 2: finish pooling + h = tanh(pooled @ w_proj^T) * w_out -> partial
// logits. grid = 256 blocks (chunk = bid>>3, hgroup = bid&7). tseg = 16.
// ---------------------------------------------------------------------------
__global__ void proj_logits(const float* __restrict__ part,
                            const float* __restrict__ w_proj,
                            const float* __restrict__ w_out,
                            float* __restrict__ logits_part) {
    __shared__ float pooled[C_SZ];
    __shared__ float red[32];
    const int bid   = blockIdx.x;
    const int chunk = bid >> 3;
    const int hg    = bid & 7;
    const int tid   = threadIdx.x;

    f32x4 acc = (f32x4)(0.f);
    for (int seg = 0; seg < 16; ++seg) {
        acc += ((const f32x4*)(part + ((size_t)seg * 32 + chunk) * C_SZ))[tid];
    }
    const float inv = 1.0f / (float)T_SZ;
    ((f32x4*)pooled)[tid] = acc * inv;
    __syncthreads();

    const int h   = hg * 32 + (tid >> 3);
    const int sub = tid & 7;
    const f32x4* wrow = (const f32x4*)(w_proj + (size_t)h * C_SZ);
    const f32x4* pl   = (const f32x4*)pooled;
    float dot = 0.f;
#pragma unroll 8
    for (int j = 0; j < 32; ++j) {
        const int c4 = sub * 32 + j;
        f32x4 w = wrow[c4];
        f32x4 p = pl[c4];
        f32x4 m = w * p;
        dot += m.x + m.y + m.z + m.w;
    }
    dot += __shfl_xor(dot, 1, 64);
    dot += __shfl_xor(dot, 2, 64);
    dot += __shfl_xor(dot, 4, 64);
    if (sub == 0) red[tid >> 3] = tanhf(dot) * w_out[h];
    __syncthreads();
    if (tid == 0) {
        float s = 0.f;
        for (int i = 0; i < 32; ++i) s += red[i];
        logits_part[chunk * 8 + hg] = s;
    }
}

// ---------------------------------------------------------------------------
// Kernel 3: weights, then blend from the int8 copy.
// u32x2 loads (8 B/lane), two contiguous f32x4 regular stores.
// ---------------------------------------------------------------------------
__global__ void mix_q(const u32* __restrict__ qs,
                      const float* __restrict__ logits_part,
                      float* __restrict__ out) {
    __shared__ float lp[256];
    __shared__ float lg[32];
    __shared__ float wgt[B_SZ][4];
    const int tid = threadIdx.x;
    compute_weights(logits_part, lp, lg, wgt, tid);

    const size_t n2tot = (size_t)B_SZ * T_SZ * C_SZ / 8;   // 2^21 u32x2 units
    const u32x2* q2 = (const u32x2*)qs;
    f32x4* dst = (f32x4*)out;
    for (size_t n = (size_t)blockIdx.x * blockDim.x + tid;
         n < n2tot;
         n += (size_t)gridDim.x * blockDim.x) {
        const int b = (int)(n >> 18);             // per-b: 2^18 u32x2
        const size_t r2 = n & ((1u << 18) - 1);
        const float w0 = wgt[b][0] * QSCALE;
        const float w1 = wgt[b][1] * QSCALE;
        const float w2 = wgt[b][2] * QSCALE;
        const float w3 = wgt[b][3] * QSCALE;
        u32x2 x0 = q2[((size_t)(0 * B_SZ + b) << 18) + r2];
        u32x2 x1 = q2[((size_t)(1 * B_SZ + b) << 18) + r2];
        u32x2 x2 = q2[((size_t)(2 * B_SZ + b) << 18) + r2];
        u32x2 x3 = q2[((size_t)(3 * B_SZ + b) << 18) + r2];
        f32x4 oa = w0 * dec4(x0.x) + w1 * dec4(x1.x) + w2 * dec4(x2.x) + w3 * dec4(x3.x);
        f32x4 ob = w0 * dec4(x0.y) + w1 * dec4(x1.y) + w2 * dec4(x2.y) + w3 * dec4(x3.y);
        const size_t o = ((size_t)b << 19) + r2 * 2;
        dst[o]     = oa;
        dst[o + 1] = ob;
    }
}

// ---------------------------------------------------------------------------
// Kernel 3 (fallback, fp32): blend straight from branches.
// ---------------------------------------------------------------------------
__global__ void mix_kernel(const float* __restrict__ br,
                           const float* __restrict__ logits_part,
                           float* __restrict__ out) {
    __shared__ float lp[256];
    __shared__ float lg[32];
    __shared__ float wgt[B_SZ][4];
    const int tid = threadIdx.x;
    compute_weights(logits_part, lp, lg, wgt, tid);

    const size_t n4total = (size_t)B_SZ * T_SZ * C_SZ / 4;
    const size_t btc4 = (size_t)T_SZ * C_SZ / 4;            // 2^19
    const f32x4* src = (const f32x4*)br;
    f32x4* dst = (f32x4*)out;
    for (size_t n = (size_t)blockIdx.x * blockDim.x + tid;
         n < n4total;
         n += (size_t)gridDim.x * blockDim.x) {
        const int b = (int)(n >> 19);
        const size_t r = n & (btc4 - 1);
        const float w0 = wgt[b][0], w1 = wgt[b][1], w2 = wgt[b][2], w3 = wgt[b][3];
        f32x4 v0 = src[((size_t)(0 * B_SZ + b)) * btc4 + r];
        f32x4 v1 = src[((size_t)(1 * B_SZ + b)) * btc4 + r];
        f32x4 v2 = src[((size_t)(2 * B_SZ + b)) * btc4 + r];
        f32x4 v3 = src[((size_t)(3 * B_SZ + b)) * btc4 + r];
        f32x4 o = w0 * v0 + w1 * v1 + w2 * v2 + w3 * v3;
        __builtin_nontemporal_store(o, &dst[n]);
    }
}

extern "C" void kernel_launch(void* const* d_in, const int* in_sizes, int n_in,
                              void* d_out, int out_size, void* d_ws, size_t ws_size,
                              hipStream_t stream) {
    const float* branches = (const float*)d_in[0];
    const float* w_proj   = (const float*)d_in[1];
    const float* w_out    = (const float*)d_in[2];
    float* out = (float*)d_out;

    const size_t qs_words  = (size_t)4 * B_SZ * T_SZ * (C_SZ / 4);  // 64 MiB
    const size_t part_need = (size_t)16 * 32 * C_SZ;                // 2 MiB floats
    const size_t fast_need = qs_words * sizeof(u32) + (part_need + 256) * sizeof(float);

    if (ws_size >= fast_need) {
        u32*   qs          = (u32*)d_ws;
        float* part        = (float*)(qs + qs_words);
        float* logits_part = part + part_need;

        pool_quant<<<512, 256, 0, stream>>>(branches, part, qs);
        proj_logits<<<256, 256, 0, stream>>>(part, w_proj, w_out, logits_part);
        mix_q<<<2048, 256, 0, stream>>>(qs, logits_part, out);
    } else {
        float* ws = (float*)d_ws;
        float* part        = ws;
        float* logits_part = ws + part_need;

        pool_partial<<<512, 256, 0, stream>>>(branches, part);
        proj_logits<<<256, 256, 0, stream>>>(part, w_proj, w_out, logits_part);
        mix_kernel<<<2048, 256, 0, stream>>>(branches, logits_part, out);
    }
}

// Round 14
// 101.755 us; speedup vs baseline: 1.1048x; 1.1048x over previous
//
#include <hip/hip_runtime.h>
#include <math.h>

#define B_SZ 8
#define T_SZ 2048
#define C_SZ 1024
#define EPSF 1e-6f
#define QSCALE (6.5f / 127.0f)
#define QINV   (127.0f / 6.5f)

typedef float        f32x4 __attribute__((ext_vector_type(4)));
typedef unsigned int u32;
typedef u32          u32x2 __attribute__((ext_vector_type(2)));

// ---------------------------------------------------------------------------
// logits_part (256 floats) -> sinkhorn -> wgt[B][4]. Call with 256 threads.
// ---------------------------------------------------------------------------
__device__ __forceinline__ void compute_weights(const float* __restrict__ logits_part,
                                                float lp[256], float lg[32],
                                                float wgt[B_SZ][4], int tid) {
    lp[tid] = logits_part[tid];
    __syncthreads();
    if (tid < 32) {
        float s = 0.f;
#pragma unroll
        for (int g = 0; g < 8; ++g) s += lp[tid * 8 + g];
        lg[tid] = s;               // logits[b*4+k]
    }
    __syncthreads();
    if (tid < B_SZ) {
        int b = tid;
        float L[4];
#pragma unroll
        for (int i = 0; i < 4; ++i) L[i] = lg[b * 4 + i];
        float mx = fmaxf(fmaxf(L[0], L[1]), fmaxf(L[2], L[3]));
        float m = 2.0f * mx;
        float t[4][4];
#pragma unroll
        for (int i = 0; i < 4; ++i)
#pragma unroll
            for (int j = 0; j < 4; ++j)
                t[i][j] = fmaxf(expf(L[i] + L[j] - m), EPSF);
#pragma unroll
        for (int it = 0; it < 5; ++it) {
#pragma unroll
            for (int i = 0; i < 4; ++i) {
                float rs = t[i][0] + t[i][1] + t[i][2] + t[i][3] + EPSF;
#pragma unroll
                for (int j = 0; j < 4; ++j) t[i][j] /= rs;
            }
#pragma unroll
            for (int j = 0; j < 4; ++j) {
                float cs = t[0][j] + t[1][j] + t[2][j] + t[3][j] + EPSF;
#pragma unroll
                for (int i = 0; i < 4; ++i) t[i][j] /= cs;
            }
        }
#pragma unroll
        for (int i = 0; i < 4; ++i) {
            float rs = t[i][0] + t[i][1] + t[i][2] + t[i][3] + EPSF;
#pragma unroll
            for (int j = 0; j < 4; ++j) t[i][j] /= rs;
        }
        float w[4];
#pragma unroll
        for (int j = 0; j < 4; ++j)
            w[j] = 0.25f * (t[0][j] + t[1][j] + t[2][j] + t[3][j]);
        float s = w[0] + w[1] + w[2] + w[3] + EPSF;
#pragma unroll
        for (int j = 0; j < 4; ++j) w[j] /= s;
        bool fin = isfinite(w[0]) && isfinite(w[1]) && isfinite(w[2]) && isfinite(w[3]);
#pragma unroll
        for (int j = 0; j < 4; ++j)
            wgt[b][j] = fin ? w[j] : 0.25f;
    }
    __syncthreads();
}

__device__ __forceinline__ u32 quant4(f32x4 v) {
    f32x4 q = v * QINV;
    int q0 = (int)rintf(fminf(fmaxf(q.x, -127.f), 127.f));
    int q1 = (int)rintf(fminf(fmaxf(q.y, -127.f), 127.f));
    int q2 = (int)rintf(fminf(fmaxf(q.z, -127.f), 127.f));
    int q3 = (int)rintf(fminf(fmaxf(q.w, -127.f), 127.f));
    return (u32)(q0 & 255) | ((u32)(q1 & 255) << 8) |
           ((u32)(q2 & 255) << 16) | ((u32)(q3 & 255) << 24);
}

__device__ __forceinline__ f32x4 dec4(u32 x) {
    f32x4 r;
    r.x = (float)(signed char)(x & 0xFF);
    r.y = (float)(signed char)((x >> 8) & 0xFF);
    r.z = (float)(signed char)((x >> 16) & 0xFF);
    r.w = (float)(signed char)((x >> 24) & 0xFF);
    return r;
}

// ---------------------------------------------------------------------------
// Kernel 1: partial mean over T + int8 quantized copy. (R12 optimum)
// 512 blocks, 256 threads, 128 rows/block. NT loads on branches — R13 A/B
// PROVED this is worth ~10 us: the cyclic 268MB stream is 0%-hit in L3
// anyway, and NOT allocating it preserves the 64 MiB qs copy's L3 residency
// for mix_q. 8-row load batches: 16 loads in flight per thread.
// ---------------------------------------------------------------------------
__global__ void pool_quant(const float* __restrict__ br,
                           float* __restrict__ part,
                           u32* __restrict__ qs) {
    const int chunk = blockIdx.x & 31;   // b*4 + k
    const int seg   = blockIdx.x >> 5;   // 0..15
    const int b = chunk >> 2;
    const int k = chunk & 3;
    const int t0 = seg * 128;

    const f32x4* src = (const f32x4*)(br + (size_t)(k * B_SZ + b) * T_SZ * C_SZ);
    u32* qdst = qs + (size_t)(k * B_SZ + b) * T_SZ * (C_SZ / 4);
    const int c4 = threadIdx.x;          // 0..255 covers C/4

    f32x4 acc0 = (f32x4)(0.f), acc1 = (f32x4)(0.f);
    f32x4 acc2 = (f32x4)(0.f), acc3 = (f32x4)(0.f);
    for (int t = t0; t < t0 + 128; t += 8) {
        const size_t r0 = (size_t)t * (C_SZ / 4) + c4;
        f32x4 v0 = __builtin_nontemporal_load(&src[r0 + 0 * (C_SZ / 4)]);
        f32x4 v1 = __builtin_nontemporal_load(&src[r0 + 1 * (C_SZ / 4)]);
        f32x4 v2 = __builtin_nontemporal_load(&src[r0 + 2 * (C_SZ / 4)]);
        f32x4 v3 = __builtin_nontemporal_load(&src[r0 + 3 * (C_SZ / 4)]);
        f32x4 v4 = __builtin_nontemporal_load(&src[r0 + 4 * (C_SZ / 4)]);
        f32x4 v5 = __builtin_nontemporal_load(&src[r0 + 5 * (C_SZ / 4)]);
        f32x4 v6 = __builtin_nontemporal_load(&src[r0 + 6 * (C_SZ / 4)]);
        f32x4 v7 = __builtin_nontemporal_load(&src[r0 + 7 * (C_SZ / 4)]);
        acc0 += v0; acc1 += v1; acc2 += v2; acc3 += v3;
        acc0 += v4; acc1 += v5; acc2 += v6; acc3 += v7;
        qdst[r0 + 0 * (C_SZ / 4)] = quant4(v0);
        qdst[r0 + 1 * (C_SZ / 4)] = quant4(v1);
        qdst[r0 + 2 * (C_SZ / 4)] = quant4(v2);
        qdst[r0 + 3 * (C_SZ / 4)] = quant4(v3);
        qdst[r0 + 4 * (C_SZ / 4)] = quant4(v4);
        qdst[r0 + 5 * (C_SZ / 4)] = quant4(v5);
        qdst[r0 + 6 * (C_SZ / 4)] = quant4(v6);
        qdst[r0 + 7 * (C_SZ / 4)] = quant4(v7);
    }
    f32x4 acc = (acc0 + acc1) + (acc2 + acc3);
    ((f32x4*)(part + ((size_t)seg * 32 + chunk) * C_SZ))[c4] = acc;
}

// ---------------------------------------------------------------------------
// Kernel 1 (fallback, fp32): partial mean only.
// ---------------------------------------------------------------------------
__global__ void pool_partial(const float* __restrict__ br,
                             float* __restrict__ part) {
    const int chunk = blockIdx.x & 31;
    const int seg   = blockIdx.x >> 5;
    const int b = chunk >> 2;
    const int k = chunk & 3;
    const int t0 = seg * 128;

    const f32x4* src = (const f32x4*)(br + (size_t)(k * B_SZ + b) * T_SZ * C_SZ);
    const int c4 = threadIdx.x;
    f32x4 acc = (f32x4)(0.f);
#pragma unroll 4
    for (int t = t0; t < t0 + 128; ++t) {
        acc += src[(size_t)t * (C_SZ / 4) + c4];
    }
    ((f32x4*)(part + ((size_t)seg * 32 + chunk) * C_SZ))[c4] = acc;
}

// ---------------------------------------------------------------------------
// Kernel 2: finish pooling + h = tanh(pooled @ w_proj^T) * w_out -> partial
// logits. grid = 256 blocks (chunk = bid>>3, hgroup = bid&7). tseg = 16.
// ---------------------------------------------------------------------------
__global__ void proj_logits(const float* __restrict__ part,
                            const float* __restrict__ w_proj,
                            const float* __restrict__ w_out,
                            float* __restrict__ logits_part) {
    __shared__ float pooled[C_SZ];
    __shared__ float red[32];
    const int bid   = blockIdx.x;
    const int chunk = bid >> 3;
    const int hg    = bid & 7;
    const int tid   = threadIdx.x;

    f32x4 acc = (f32x4)(0.f);
    for (int seg = 0; seg < 16; ++seg) {
        acc += ((const f32x4*)(part + ((size_t)seg * 32 + chunk) * C_SZ))[tid];
    }
    const float inv = 1.0f / (float)T_SZ;
    ((f32x4*)pooled)[tid] = acc * inv;
    __syncthreads();

    const int h   = hg * 32 + (tid >> 3);
    const int sub = tid & 7;
    const f32x4* wrow = (const f32x4*)(w_proj + (size_t)h * C_SZ);
    const f32x4* pl   = (const f32x4*)pooled;
    float dot = 0.f;
#pragma unroll 8
    for (int j = 0; j < 32; ++j) {
        const int c4 = sub * 32 + j;
        f32x4 w = wrow[c4];
        f32x4 p = pl[c4];
        f32x4 m = w * p;
        dot += m.x + m.y + m.z + m.w;
    }
    dot += __shfl_xor(dot, 1, 64);
    dot += __shfl_xor(dot, 2, 64);
    dot += __shfl_xor(dot, 4, 64);
    if (sub == 0) red[tid >> 3] = tanhf(dot) * w_out[h];
    __syncthreads();
    if (tid == 0) {
        float s = 0.f;
        for (int i = 0; i < 32; ++i) s += red[i];
        logits_part[chunk * 8 + hg] = s;
    }
}

// ---------------------------------------------------------------------------
// Kernel 3: weights, then blend from the int8 copy (L3-resident thanks to
// pool's NT loads). u32x2 loads, two contiguous f32x4 regular stores.
// ---------------------------------------------------------------------------
__global__ void mix_q(const u32* __restrict__ qs,
                      const float* __restrict__ logits_part,
                      float* __restrict__ out) {
    __shared__ float lp[256];
    __shared__ float lg[32];
    __shared__ float wgt[B_SZ][4];
    const int tid = threadIdx.x;
    compute_weights(logits_part, lp, lg, wgt, tid);

    const size_t n2tot = (size_t)B_SZ * T_SZ * C_SZ / 8;   // 2^21 u32x2 units
    const u32x2* q2 = (const u32x2*)qs;
    f32x4* dst = (f32x4*)out;
    for (size_t n = (size_t)blockIdx.x * blockDim.x + tid;
         n < n2tot;
         n += (size_t)gridDim.x * blockDim.x) {
        const int b = (int)(n >> 18);             // per-b: 2^18 u32x2
        const size_t r2 = n & ((1u << 18) - 1);
        const float w0 = wgt[b][0] * QSCALE;
        const float w1 = wgt[b][1] * QSCALE;
        const float w2 = wgt[b][2] * QSCALE;
        const float w3 = wgt[b][3] * QSCALE;
        u32x2 x0 = q2[((size_t)(0 * B_SZ + b) << 18) + r2];
        u32x2 x1 = q2[((size_t)(1 * B_SZ + b) << 18) + r2];
        u32x2 x2 = q2[((size_t)(2 * B_SZ + b) << 18) + r2];
        u32x2 x3 = q2[((size_t)(3 * B_SZ + b) << 18) + r2];
        f32x4 oa = w0 * dec4(x0.x) + w1 * dec4(x1.x) + w2 * dec4(x2.x) + w3 * dec4(x3.x);
        f32x4 ob = w0 * dec4(x0.y) + w1 * dec4(x1.y) + w2 * dec4(x2.y) + w3 * dec4(x3.y);
        const size_t o = ((size_t)b << 19) + r2 * 2;
        dst[o]     = oa;
        dst[o + 1] = ob;
    }
}

// ---------------------------------------------------------------------------
// Kernel 3 (fallback, fp32): blend straight from branches.
// ---------------------------------------------------------------------------
__global__ void mix_kernel(const float* __restrict__ br,
                           const float* __restrict__ logits_part,
                           float* __restrict__ out) {
    __shared__ float lp[256];
    __shared__ float lg[32];
    __shared__ float wgt[B_SZ][4];
    const int tid = threadIdx.x;
    compute_weights(logits_part, lp, lg, wgt, tid);

    const size_t n4total = (size_t)B_SZ * T_SZ * C_SZ / 4;
    const size_t btc4 = (size_t)T_SZ * C_SZ / 4;            // 2^19
    const f32x4* src = (const f32x4*)br;
    f32x4* dst = (f32x4*)out;
    for (size_t n = (size_t)blockIdx.x * blockDim.x + tid;
         n < n4total;
         n += (size_t)gridDim.x * blockDim.x) {
        const int b = (int)(n >> 19);
        const size_t r = n & (btc4 - 1);
        const float w0 = wgt[b][0], w1 = wgt[b][1], w2 = wgt[b][2], w3 = wgt[b][3];
        f32x4 v0 = src[((size_t)(0 * B_SZ + b)) * btc4 + r];
        f32x4 v1 = src[((size_t)(1 * B_SZ + b)) * btc4 + r];
        f32x4 v2 = src[((size_t)(2 * B_SZ + b)) * btc4 + r];
        f32x4 v3 = src[((size_t)(3 * B_SZ + b)) * btc4 + r];
        f32x4 o = w0 * v0 + w1 * v1 + w2 * v2 + w3 * v3;
        __builtin_nontemporal_store(o, &dst[n]);
    }
}

extern "C" void kernel_launch(void* const* d_in, const int* in_sizes, int n_in,
                              void* d_out, int out_size, void* d_ws, size_t ws_size,
                              hipStream_t stream) {
    const float* branches = (const float*)d_in[0];
    const float* w_proj   = (const float*)d_in[1];
    const float* w_out    = (const float*)d_in[2];
    float* out = (float*)d_out;

    const size_t qs_words  = (size_t)4 * B_SZ * T_SZ * (C_SZ / 4);  // 64 MiB
    const size_t part_need = (size_t)16 * 32 * C_SZ;                // 2 MiB floats
    const size_t fast_need = qs_words * sizeof(u32) + (part_need + 256) * sizeof(float);

    if (ws_size >= fast_need) {
        u32*   qs          = (u32*)d_ws;
        float* part        = (float*)(qs + qs_words);
        float* logits_part = part + part_need;

        pool_quant<<<512, 256, 0, stream>>>(branches, part, qs);
        proj_logits<<<256, 256, 0, stream>>>(part, w_proj, w_out, logits_part);
        mix_q<<<2048, 256, 0, stream>>>(qs, logits_part, out);
    } else {
        float* ws = (float*)d_ws;
        float* part        = ws;
        float* logits_part = ws + part_need;

        pool_partial<<<512, 256, 0, stream>>>(branches, part);
        proj_logits<<<256, 256, 0, stream>>>(part, w_proj, w_out, logits_part);
        mix_kernel<<<2048, 256, 0, stream>>>(branches, logits_part, out);
    }
}